// Round 9
// baseline (264.546 us; speedup 1.0000x reference)
//
#include <hip/hip_runtime.h>
#include <stddef.h>

#define B_ 2
#define L_ 384
#define D_ 1024
#define K_ 128
#define H_ 32

#define MINV (-3.402823466e38f)
// Exported -inf sentinel: must stay FINITE after bf16 rounding (bf16 max ~3.39e38).
#define NEG_BIG (-1.0e38f)
#define SCALING_ 0.08838834764831845f
#define INV_SQRT_2PI 0.3989422804014327f

typedef __attribute__((ext_vector_type(8))) short bf16x8;
typedef __attribute__((ext_vector_type(4))) float f32x4;

__device__ __forceinline__ float finitize(float x) {
    return fminf(fmaxf(x, -1.0e38f), 1.0e38f);
}
__device__ __forceinline__ unsigned short f2bf(float x) {
    unsigned int u = __float_as_uint(x);
    u += 0x7FFFu + ((u >> 16) & 1u);
    return (unsigned short)(u >> 16);
}
__device__ __forceinline__ unsigned short f2bf_rtz(float x) {
    return (unsigned short)(__float_as_uint(x) >> 16);
}
// tanh-form gelu: max abs err ~3e-4, 1 exp + 1 rcp
__device__ __forceinline__ float gelu_tanh(float x) {
    const float x2 = x * x;
    const float z = x * fmaf(0.0356774081f, x2, 0.7978845608f);
    const float e = __expf(2.0f * z);
    const float t = fmaf(-2.0f, __builtin_amdgcn_rcpf(e + 1.0f), 1.0f);
    const float hx = 0.5f * x;
    return fmaf(hx, t, hx);
}

// ---------------------------------------------------------------------------
// prep+sin fused: blocks [0,2324) convert weights f32->bf16 (594944 float4
// chunks); blocks [2324,3092) compute sinusoidal features + padding_mask.
// ---------------------------------------------------------------------------
__global__ __launch_bounds__(256) void prep_sin_kernel(
    const float* __restrict__ W1, const float* __restrict__ W2,
    const float* __restrict__ Wpfe, const float* __restrict__ Wproj,
    const float* __restrict__ Wt1, const float* __restrict__ Wt2,
    unsigned short* __restrict__ W1bf, unsigned short* __restrict__ W2bf,
    unsigned short* __restrict__ Wpfebf, unsigned short* __restrict__ Wprojbf,
    unsigned short* __restrict__ Wt1bf, unsigned short* __restrict__ Wt2bf,
    const float* __restrict__ time_step, const unsigned char* __restrict__ clean,
    const int* __restrict__ token, unsigned short* __restrict__ sin_bf,
    float* __restrict__ padout)
{
    const int blk = blockIdx.x;
    if (blk < 2324) {
        const int i = blk * 256 + threadIdx.x;
        const float* src; unsigned short* dst; int off;
        if (i < 4096)        { src = W1;    dst = W1bf;    off = i; }
        else if (i < 5120)   { src = W2;    dst = W2bf;    off = i - 4096; }
        else if (i < 37888)  { src = Wpfe;  dst = Wpfebf;  off = i - 5120; }
        else if (i < 70656)  { src = Wproj; dst = Wprojbf; off = i - 37888; }
        else if (i < 332800) { src = Wt1;   dst = Wt1bf;   off = i - 70656; }
        else                 { src = Wt2;   dst = Wt2bf;   off = i - 332800; }
        const float4 v = ((const float4*)src)[off];
        ushort4 p; p.x = f2bf(v.x); p.y = f2bf(v.y); p.z = f2bf(v.z); p.w = f2bf(v.w);
        ((ushort4*)dst)[off] = p;
    } else {
        const int row = blk - 2324;
        if (threadIdx.x == 0) padout[row] = (token[row] == 0) ? 1.0f : 0.0f;
        const float t = (clean[row] ? 0.0f : time_step[row]) * 1000.0f;
        for (int k = threadIdx.x; k < 512; k += 256) {
            const float f = __expf(-9.210340371976184f * (float)k * (1.0f / 512.0f));
            const float ang = t * f;
            sin_bf[(size_t)row * D_ + k]       = f2bf(__sinf(ang));
            sin_bf[(size_t)row * D_ + 512 + k] = f2bf(__cosf(ang));
        }
    }
}

// ---------------------------------------------------------------------------
// time-MLP NT GEMM, all-bf16: BM=32, BN=64, BK=128 (8 iters), reg prefetch.
// act=1: silu->bf16; act=0: f32 out.
// ---------------------------------------------------------------------------
__global__ __launch_bounds__(256) void gemm_ts(const unsigned short* __restrict__ A,
                                               const unsigned short* __restrict__ Bw,
                                               const float* __restrict__ bias,
                                               void* __restrict__ Cv,
                                               int M, int N, int Kd, int act)
{
    __shared__ unsigned short sA[32][136];
    __shared__ unsigned short sB[64][136];
    const int tid  = threadIdx.x;
    const int lane = tid & 63;
    const int wave = tid >> 6;
    const int l15  = lane & 15;
    const int quad = lane >> 4;
    const int mt   = wave & 1;
    const int np   = wave >> 1;
    const int m0 = blockIdx.y * 32, n0 = blockIdx.x * 64;

    // A: 32x128 bf16 = 512 uint4 chunks (2/thr); B: 64x128 = 1024 (4/thr)
    const int c8  = (tid & 15) * 8;
    const int ar0 = tid >> 4, ar1 = (tid + 256) >> 4;

    f32x4 acc[2];
#pragma unroll
    for (int t = 0; t < 2; ++t) acc[t] = (f32x4){0.f, 0.f, 0.f, 0.f};

    uint4 ra0 = *(const uint4*)&A[(size_t)(m0 + ar0) * Kd + c8];
    uint4 ra1 = *(const uint4*)&A[(size_t)(m0 + ar1) * Kd + c8];
    uint4 rb[4];
#pragma unroll
    for (int c = 0; c < 4; ++c)
        rb[c] = *(const uint4*)&Bw[(size_t)(n0 + ((tid + c * 256) >> 4)) * Kd + c8];

    for (int k0 = 0; k0 < Kd; k0 += 128) {
        *(uint4*)&sA[ar0][c8] = ra0;
        *(uint4*)&sA[ar1][c8] = ra1;
#pragma unroll
        for (int c = 0; c < 4; ++c) *(uint4*)&sB[(tid + c * 256) >> 4][c8] = rb[c];
        __syncthreads();
        if (k0 + 128 < Kd) {
            ra0 = *(const uint4*)&A[(size_t)(m0 + ar0) * Kd + k0 + 128 + c8];
            ra1 = *(const uint4*)&A[(size_t)(m0 + ar1) * Kd + k0 + 128 + c8];
#pragma unroll
            for (int c = 0; c < 4; ++c)
                rb[c] = *(const uint4*)&Bw[(size_t)(n0 + ((tid + c * 256) >> 4)) * Kd + k0 + 128 + c8];
        }
#pragma unroll
        for (int kk = 0; kk < 128; kk += 32) {
            const bf16x8 av = *(const bf16x8*)&sA[mt * 16 + l15][kk + quad * 8];
#pragma unroll
            for (int t = 0; t < 2; ++t) {
                const bf16x8 bv = *(const bf16x8*)&sB[(np * 2 + t) * 16 + l15][kk + quad * 8];
                acc[t] = __builtin_amdgcn_mfma_f32_16x16x32_bf16(av, bv, acc[t], 0, 0, 0);
            }
        }
        __syncthreads();
    }
#pragma unroll
    for (int t = 0; t < 2; ++t) {
        const int nc = n0 + (np * 2 + t) * 16 + l15;
        const float bv = bias[nc];
#pragma unroll
        for (int r = 0; r < 4; ++r) {
            const int mr = m0 + mt * 16 + quad * 4 + r;
            float v = acc[t][r] + bv;
            if (act) {
                v = v / (1.0f + __expf(-v));
                ((unsigned short*)Cv)[(size_t)mr * N + nc] = f2bf(v);
            } else {
                ((float*)Cv)[(size_t)mr * N + nc] = v;
            }
        }
    }
}

// ---------------------------------------------------------------------------
// pos_embedding MFMA GEMM fused with combine. BM=32, BN=64, grid (16, 24).
// ---------------------------------------------------------------------------
__global__ __launch_bounds__(256) void pe_gemm(const unsigned short* __restrict__ pfe_bf,
                                               const unsigned short* __restrict__ ef_bf,
                                               const unsigned short* __restrict__ Wpfebf,
                                               const unsigned short* __restrict__ Wprojbf,
                                               const float* __restrict__ bproj,
                                               const int* __restrict__ token,
                                               const float* __restrict__ embed_w,
                                               const float* __restrict__ te,
                                               float* __restrict__ outPE,
                                               float* __restrict__ outX)
{
    __shared__ unsigned short sA[32][136];
    __shared__ unsigned short sB[64][136];
    const int tid  = threadIdx.x;
    const int lane = tid & 63;
    const int wave = tid >> 6;
    const int l15  = lane & 15;
    const int quad = lane >> 4;
    const int mt   = wave & 1;
    const int np   = wave >> 1;
    const int m0 = blockIdx.y * 32, n0 = blockIdx.x * 64;

    f32x4 acc[2];
#pragma unroll
    for (int t = 0; t < 2; ++t) acc[t] = (f32x4){0.f, 0.f, 0.f, 0.f};

    for (int phase = 0; phase < 2; ++phase) {
        const unsigned short* Ap = phase ? ef_bf : pfe_bf;       // (768,128)
        const unsigned short* Bp = phase ? Wprojbf : Wpfebf;     // (1024,128)
#pragma unroll
        for (int e = tid; e < 512; e += 256) {
            const int r = e >> 4, c8 = (e & 15) * 8;
            *(uint4*)&sA[r][c8] = *(const uint4*)&Ap[(size_t)(m0 + r) * K_ + c8];
        }
#pragma unroll
        for (int e = tid; e < 1024; e += 256) {
            const int r = e >> 4, c8 = (e & 15) * 8;
            *(uint4*)&sB[r][c8] = *(const uint4*)&Bp[(size_t)(n0 + r) * K_ + c8];
        }
        __syncthreads();
#pragma unroll
        for (int ks = 0; ks < 4; ++ks) {
            const bf16x8 av = *(const bf16x8*)&sA[mt * 16 + l15][ks * 32 + quad * 8];
#pragma unroll
            for (int t = 0; t < 2; ++t) {
                const bf16x8 bv = *(const bf16x8*)&sB[(np * 2 + t) * 16 + l15][ks * 32 + quad * 8];
                acc[t] = __builtin_amdgcn_mfma_f32_16x16x32_bf16(av, bv, acc[t], 0, 0, 0);
            }
        }
        __syncthreads();
    }
#pragma unroll
    for (int t = 0; t < 2; ++t) {
        const int nc = n0 + (np * 2 + t) * 16 + l15;
        const float bv = bproj[nc];
#pragma unroll
        for (int r = 0; r < 4; ++r) {
            const int mr = m0 + mt * 16 + quad * 4 + r;
            const int tok = token[mr];
            const float pe = (tok == 0) ? 0.0f : (acc[t][r] + bv);
            outPE[(size_t)mr * D_ + nc] = pe;
            outX[(size_t)mr * D_ + nc] = embed_w[(size_t)tok * D_ + nc]
                                       + te[(size_t)mr * D_ + nc] + pe;
        }
    }
}

// ---------------------------------------------------------------------------
// edge_main: 2 blocks per (b,i) row; block handles 192 j-columns (6 tiles).
// Writes pab (masked), raw d-sums -> ws_d, partial ef col-sums -> ws_efp.
// ---------------------------------------------------------------------------
__global__ __launch_bounds__(256, 4) void edge_main(
    const int* __restrict__ token_id,
    const float* __restrict__ pos,
    const int* __restrict__ nte,
    const float* __restrict__ gbf_means,
    const float* __restrict__ gbf_stds,
    const float* __restrict__ gbf_mul,
    const float* __restrict__ gbf_bias,
    const float* __restrict__ b1,
    const float* __restrict__ b2,
    const unsigned short* __restrict__ W1bf,
    const unsigned short* __restrict__ W2bf,
    float* __restrict__ ws_d,        // (B*L, 384) raw head-sums
    float* __restrict__ ws_efp,      // (B*L, 2, 128) partial ef sums
    float* __restrict__ out_pab)
{
    const int bx = blockIdx.x;
    const int row = bx >> 1;
    const int half = bx & 1;
    const int b = row / L_;
    const int i = row - b * L_;
    const int j0 = half * 192;
    const int tid = threadIdx.x;

    const int tok_i = token_id[row];
    if (tok_i == 0) {
        for (int idx = tid; idx < H_ * 192; idx += 256) {
            const int h = idx / 192, j = idx - h * 192;
            out_pab[((size_t)(b * H_ + h) * L_ + i) * L_ + j0 + j] = 0.0f;
        }
        return;
    }

    __shared__ unsigned short sEF[2][32][136];
    __shared__ unsigned short sACT[32][136];
    __shared__ float sGab[32][33];
    __shared__ float sY[192];
    __shared__ unsigned char sPadCol[192];

    for (int jl = tid; jl < 192; jl += 256)
        sPadCol[jl] = (token_id[b * L_ + j0 + jl] == 0) ? 1 : 0;

    const float px = pos[(size_t)row * 3 + 0];
    const float py = pos[(size_t)row * 3 + 1];
    const float pz = pos[(size_t)row * 3 + 2];
    for (int jl = tid; jl < 192; jl += 256) {
        const int jg2 = j0 + jl;
        const float dx = px - pos[(size_t)(b * L_ + jg2) * 3 + 0];
        const float dy = py - pos[(size_t)(b * L_ + jg2) * 3 + 1];
        const float dz = pz - pos[(size_t)(b * L_ + jg2) * 3 + 2];
        const float dist = sqrtf(fmaxf(dx * dx + dy * dy + dz * dz, 1e-12f));
        const size_t eoff = ((size_t)(b * L_ + i) * L_ + jg2) * 2;
        const int e0 = nte[eoff], e1 = nte[eoff + 1];
        sY[jl] = (gbf_mul[e0] + gbf_mul[e1]) * dist + (gbf_bias[e0] + gbf_bias[e1]);
    }

    // MFMA lane mapping
    const int lane = tid & 63;
    const int wave = tid >> 6;
    const int l15  = lane & 15;
    const int quad = lane >> 4;
    const int mt   = wave & 1;
    const int ntb  = (wave >> 1) * 4;
    float rb1[4];
#pragma unroll
    for (int nt = 0; nt < 4; ++nt) rb1[nt] = b1[(ntb + nt) * 16 + l15];
    const int hc = (wave >> 1) * 16 + l15;
    const float rb2 = b2[hc];
    bf16x8 w1f[4][4];
#pragma unroll
    for (int ks = 0; ks < 4; ++ks)
#pragma unroll
        for (int nt = 0; nt < 4; ++nt)
            w1f[ks][nt] = *(const bf16x8*)&W1bf[((ntb + nt) * 16 + l15) * K_ + ks * 32 + quad * 8];
    bf16x8 bv2[4];
#pragma unroll
    for (int ks = 0; ks < 4; ++ks)
        bv2[ks] = *(const bf16x8*)&W2bf[hc * K_ + ks * 32 + quad * 8];

    // ef-gen mapping: thread -> 4 j x 4 k
    const int kg4 = (tid & 31) * 4;
    const int jg  = tid >> 5;
    const int jb  = jg * 4;
    float meanv[4], istdv[4], cKv[4];
#pragma unroll
    for (int c = 0; c < 4; ++c) {
        meanv[c] = gbf_means[kg4 + c];
        const float s = fabsf(gbf_stds[kg4 + c]) + 1e-5f;
        istdv[c] = 1.0f / s;
        cKv[c]   = INV_SQRT_2PI * istdv[c];
    }
    float efs[4] = {0.f, 0.f, 0.f, 0.f};

    __syncthreads();

    // prologue: ef tile 0 (local j 0..31)
#pragma unroll
    for (int jj = 0; jj < 4; ++jj) {
        const int j = jb + jj;
        const float y = sY[j];
        const bool ok = !sPadCol[j];
        ushort4 p;
#pragma unroll
        for (int c = 0; c < 4; ++c) {
            const float a = (y - meanv[c]) * istdv[c];
            const float ef = __expf(-0.5f * a * a) * cKv[c];
            ((unsigned short*)&p)[c] = f2bf_rtz(ef);
            if (ok) efs[c] += ef;
        }
        *(ushort4*)&sEF[0][j][kg4] = p;
    }
    __syncthreads();

    for (int tile = 0; tile < 6; ++tile) {
        const int jt0 = tile * 32;     // local j base
        const int cur = tile & 1, nxt = cur ^ 1;

        // GEMM1
        f32x4 acc1[4];
#pragma unroll
        for (int nt = 0; nt < 4; ++nt) acc1[nt] = (f32x4){0.f, 0.f, 0.f, 0.f};
#pragma unroll
        for (int ks = 0; ks < 4; ++ks) {
            const bf16x8 av = *(const bf16x8*)&sEF[cur][mt * 16 + l15][ks * 32 + quad * 8];
#pragma unroll
            for (int nt = 0; nt < 4; ++nt)
                acc1[nt] = __builtin_amdgcn_mfma_f32_16x16x32_bf16(av, w1f[ks][nt], acc1[nt], 0, 0, 0);
        }

        // ef-gen next tile
        if (tile + 1 < 6) {
            const int jn0 = jt0 + 32;
#pragma unroll
            for (int jj = 0; jj < 4; ++jj) {
                const int j = jb + jj;
                const float y = sY[jn0 + j];
                const bool ok = !sPadCol[jn0 + j];
                ushort4 p;
#pragma unroll
                for (int c = 0; c < 4; ++c) {
                    const float a = (y - meanv[c]) * istdv[c];
                    const float ef = __expf(-0.5f * a * a) * cKv[c];
                    ((unsigned short*)&p)[c] = f2bf_rtz(ef);
                    if (ok) efs[c] += ef;
                }
                *(ushort4*)&sEF[nxt][j][kg4] = p;
            }
        }

        // bias + gelu -> sACT
#pragma unroll
        for (int nt = 0; nt < 4; ++nt) {
            const int kkc = (ntb + nt) * 16 + l15;
#pragma unroll
            for (int r = 0; r < 4; ++r) {
                const float v = gelu_tanh(acc1[nt][r] + rb1[nt]);
                sACT[mt * 16 + quad * 4 + r][kkc] = f2bf_rtz(v);
            }
        }
        __syncthreads();   // A

        // GEMM2
        f32x4 acc2 = (f32x4){0.f, 0.f, 0.f, 0.f};
#pragma unroll
        for (int ks = 0; ks < 4; ++ks) {
            const bf16x8 av = *(const bf16x8*)&sACT[mt * 16 + l15][ks * 32 + quad * 8];
            acc2 = __builtin_amdgcn_mfma_f32_16x16x32_bf16(av, bv2[ks], acc2, 0, 0, 0);
        }
        const int jl0 = mt * 16 + quad * 4;
#pragma unroll
        for (int r = 0; r < 4; ++r) sGab[jl0 + r][hc] = acc2[r] + rb2;
        __syncthreads();   // B

        // coalesced pab store (8 threads = one 128B line)
        {
            const int h = tid >> 3, f = tid & 7;
            const int jb2 = f * 4;
            float4 st;
#pragma unroll
            for (int r = 0; r < 4; ++r) {
                float v = finitize(sGab[jb2 + r][h]);
                if (sPadCol[jt0 + jb2 + r]) v = NEG_BIG;
                ((float*)&st)[r] = v;
            }
            *(float4*)&out_pab[((size_t)(b * H_ + h) * L_ + i) * L_ + j0 + jt0 + jb2] = st;
        }
        if (tid < 32) {    // raw d-sums over heads
            float s = 0.0f;
#pragma unroll
            for (int h = 0; h < 32; ++h) s += sGab[tid][h];
            ws_d[(size_t)row * L_ + j0 + jt0 + tid] = s;
        }
    }

    // partial ef column-sum -> ws_efp (via sACT scratch; all sACT reads done)
    {
        float* efScr = (float*)sACT;
#pragma unroll
        for (int c = 0; c < 4; ++c) efScr[jg * 128 + kg4 + c] = efs[c];
    }
    __syncthreads();
    if (tid < 128) {
        const float* efScr = (const float*)sACT;
        float s = 0.0f;
#pragma unroll
        for (int g = 0; g < 8; ++g) s += efScr[g * 128 + tid];
        ws_efp[((size_t)row * 2 + half) * 128 + tid] = s;
    }
}

// ---------------------------------------------------------------------------
// edge_post: per row softmax over masked d, pfe moments, final ef/pfe writes.
// ---------------------------------------------------------------------------
__global__ __launch_bounds__(256) void edge_post(
    const int* __restrict__ token_id,
    const unsigned char* __restrict__ is_periodic,
    const float* __restrict__ pos,
    const unsigned char* __restrict__ adj,
    const float* __restrict__ Wpos,
    const float* __restrict__ ws_d,
    const float* __restrict__ ws_efp,
    unsigned short* __restrict__ pfe_bf,
    unsigned short* __restrict__ ef_bf)
{
    const int row = blockIdx.x;
    const int tid = threadIdx.x;
    const int tok = token_id[row];
    if (tok == 0) {
        if (tid < 128) {
            pfe_bf[(size_t)row * K_ + tid] = 0;
            ef_bf[(size_t)row * K_ + tid]  = 0;
        }
        return;
    }
    const int b = row / L_;
    const int i = row - b * L_;
    const int lane = tid & 63;
    const int wave = tid >> 6;

    __shared__ float sD[L_];
    __shared__ unsigned char sPad[L_];
    __shared__ float sRed[32];

    const bool molecule = (tok <= 129) && (is_periodic[b] == 0);
    float lmax = -INFINITY;
    for (int j = tid; j < L_; j += 256) {
        const bool colpad = (token_id[b * L_ + j] == 0);
        sPad[j] = colpad ? 1 : 0;
        const bool ae = (adj[(size_t)(b * L_ + i) * L_ + j] != 0) || (!molecule);
        const float dv = (colpad || !ae) ? MINV : ws_d[(size_t)row * L_ + j];
        const float s = dv * SCALING_;
        sD[j] = s;
        lmax = fmaxf(lmax, s);
    }
#pragma unroll
    for (int off = 32; off > 0; off >>= 1) lmax = fmaxf(lmax, __shfl_xor(lmax, off));
    if (lane == 0) sRed[wave] = lmax;
    __syncthreads();
    const float smax = fmaxf(fmaxf(sRed[0], sRed[1]), fmaxf(sRed[2], sRed[3]));
    float lsum = 0.0f;
    for (int j = tid; j < L_; j += 256) {
        const float e = __expf(sD[j] - smax);
        sD[j] = e;
        lsum += e;
    }
#pragma unroll
    for (int off = 32; off > 0; off >>= 1) lsum += __shfl_xor(lsum, off);
    if (lane == 0) sRed[4 + wave] = lsum;
    __syncthreads();
    const float inv = 1.0f / (sRed[4] + sRed[5] + sRed[6] + sRed[7]);

    float a0 = 0.f, a1 = 0.f, a2 = 0.f;
    for (int j = tid; j < L_; j += 256) {
        if (!sPad[j]) {
            const float e = sD[j];
            a0 += e * pos[(size_t)(b * L_ + j) * 3 + 0];
            a1 += e * pos[(size_t)(b * L_ + j) * 3 + 1];
            a2 += e * pos[(size_t)(b * L_ + j) * 3 + 2];
        }
    }
#pragma unroll
    for (int off = 32; off > 0; off >>= 1) {
        a0 += __shfl_xor(a0, off);
        a1 += __shfl_xor(a1, off);
        a2 += __shfl_xor(a2, off);
    }
    if (lane == 0) { sRed[8 + wave] = a0; sRed[12 + wave] = a1; sRed[16 + wave] = a2; }
    __syncthreads();
    if (tid < 128) {
        const float m0 = sRed[8] + sRed[9] + sRed[10] + sRed[11];
        const float m1 = sRed[12] + sRed[13] + sRed[14] + sRed[15];
        const float m2 = sRed[16] + sRed[17] + sRed[18] + sRed[19];
        const float w0 = Wpos[tid * 3 + 0], w1 = Wpos[tid * 3 + 1], w2 = Wpos[tid * 3 + 2];
        pfe_bf[(size_t)row * K_ + tid] = f2bf((m0 * w0 + m1 * w1 + m2 * w2) * inv);
        ef_bf[(size_t)row * K_ + tid] =
            f2bf(ws_efp[(size_t)row * 256 + tid] + ws_efp[(size_t)row * 256 + 128 + tid]);
    }
}

// ---------------------------------------------------------------------------
extern "C" void kernel_launch(void* const* d_in, const int* in_sizes, int n_in,
                              void* d_out, int out_size, void* d_ws, size_t ws_size,
                              hipStream_t stream) {
    const int*           token_id    = (const int*)d_in[0];
    const unsigned char* is_periodic = (const unsigned char*)d_in[1];
    const float*         pos         = (const float*)d_in[2];
    const unsigned char* adj         = (const unsigned char*)d_in[3];
    const int*           nte         = (const int*)d_in[4];
    const float*         time_step   = (const float*)d_in[5];
    const unsigned char* clean_mask  = (const unsigned char*)d_in[6];
    const float*         embed_w     = (const float*)d_in[7];
    const float*         Wpos        = (const float*)d_in[8];
    const float*         Wpfe        = (const float*)d_in[9];
    const float*         gbf_means   = (const float*)d_in[10];
    const float*         gbf_stds    = (const float*)d_in[11];
    const float*         gbf_mul     = (const float*)d_in[12];
    const float*         gbf_bias    = (const float*)d_in[13];
    const float*         W1          = (const float*)d_in[14];
    const float*         b1          = (const float*)d_in[15];
    const float*         W2          = (const float*)d_in[16];
    const float*         b2          = (const float*)d_in[17];
    const float*         Wproj       = (const float*)d_in[18];
    const float*         bproj       = (const float*)d_in[19];
    const float*         Wt1         = (const float*)d_in[20];
    const float*         bt1         = (const float*)d_in[21];
    const float*         Wt2         = (const float*)d_in[22];
    const float*         bt2         = (const float*)d_in[23];

    float* out = (float*)d_out;
    float* out_x   = out;                 // (B,L,D)
    float* out_pad = out + 786432;        // (B,L)
    float* out_te  = out + 787200;        // (B,L,D)
    float* out_pab = out + 1573632;       // (B,H,L,L)
    float* out_pe  = out + 11010816;      // (B,L,D)

    // workspace (ushort units)
    unsigned short* wsu = (unsigned short*)d_ws;
    unsigned short* W1bf    = wsu;                 // 16384
    unsigned short* W2bf    = wsu + 16384;         // 4096
    unsigned short* Wpfebf  = wsu + 20480;         // 131072
    unsigned short* Wprojbf = wsu + 151552;        // 131072
    unsigned short* sin_bf  = wsu + 282624;        // 786432
    unsigned short* h1_bf   = wsu + 1069056;       // 786432
    unsigned short* pfe_bf  = wsu + 1855488;       // 98304
    unsigned short* ef_bf   = wsu + 1953792;       // 98304
    // Wt1bf/Wt2bf (2 MB each) in out_pab: consumed by gemm_ts before edge_main
    // overwrites every pab element.
    unsigned short* Wt1bf = (unsigned short*)out_pab;
    unsigned short* Wt2bf = Wt1bf + 1048576;
    // edge scratch lives in out_pe: written by edge_main, read by edge_post,
    // then fully overwritten by pe_gemm.
    float* ws_d   = out_pe;               // 768*384 = 294912 floats
    float* ws_efp = out_pe + 294912;      // 768*256 = 196608 floats

    prep_sin_kernel<<<dim3(3092), dim3(256), 0, stream>>>(
        W1, W2, Wpfe, Wproj, Wt1, Wt2,
        W1bf, W2bf, Wpfebf, Wprojbf, Wt1bf, Wt2bf,
        time_step, clean_mask, token_id, sin_bf, out_pad);
    gemm_ts<<<dim3(16, 24), dim3(256), 0, stream>>>(sin_bf, Wt1bf, bt1, (void*)h1_bf,
                                                    768, 1024, 1024, 1);
    gemm_ts<<<dim3(16, 24), dim3(256), 0, stream>>>(h1_bf, Wt2bf, bt2, (void*)out_te,
                                                    768, 1024, 1024, 0);
    edge_main<<<dim3(2 * B_ * L_), dim3(256), 0, stream>>>(
        token_id, pos, nte, gbf_means, gbf_stds, gbf_mul, gbf_bias,
        b1, b2, W1bf, W2bf, ws_d, ws_efp, out_pab);
    edge_post<<<dim3(B_ * L_), dim3(256), 0, stream>>>(
        token_id, is_periodic, pos, adj, Wpos, ws_d, ws_efp, pfe_bf, ef_bf);
    pe_gemm<<<dim3(16, 24), dim3(256), 0, stream>>>(pfe_bf, ef_bf, Wpfebf, Wprojbf,
                                                    bproj, token_id, embed_w, out_te,
                                                    out_pe, out_x);
}

// Round 10
// 190.566 us; speedup vs baseline: 1.3882x; 1.3882x over previous
//
#include <hip/hip_runtime.h>
#include <stddef.h>

#define B_ 2
#define L_ 384
#define D_ 1024
#define K_ 128
#define H_ 32

#define MINV (-3.402823466e38f)
// Exported -inf sentinel: must stay FINITE after bf16 rounding (bf16 max ~3.39e38).
#define NEG_BIG (-1.0e38f)
#define SCALING_ 0.08838834764831845f
#define INV_SQRT_2PI 0.3989422804014327f

typedef __attribute__((ext_vector_type(8))) short bf16x8;
typedef __attribute__((ext_vector_type(4))) float f32x4;

__device__ __forceinline__ float finitize(float x) {
    return fminf(fmaxf(x, -1.0e38f), 1.0e38f);
}
__device__ __forceinline__ unsigned short f2bf(float x) {
    unsigned int u = __float_as_uint(x);
    u += 0x7FFFu + ((u >> 16) & 1u);
    return (unsigned short)(u >> 16);
}
__device__ __forceinline__ unsigned short f2bf_rtz(float x) {
    return (unsigned short)(__float_as_uint(x) >> 16);
}
// tanh-form gelu: max abs err ~3e-4, 1 exp + 1 rcp
__device__ __forceinline__ float gelu_tanh(float x) {
    const float x2 = x * x;
    const float z = x * fmaf(0.0356774081f, x2, 0.7978845608f);
    const float e = __expf(2.0f * z);
    const float t = fmaf(-2.0f, __builtin_amdgcn_rcpf(e + 1.0f), 1.0f);
    const float hx = 0.5f * x;
    return fmaf(hx, t, hx);
}

// ---------------------------------------------------------------------------
// prep+sin fused: blocks [0,276) convert W1/W2/Wpfe/Wproj f32->bf16
// (70656 float4 chunks); blocks [276,1044) sinusoidal features + padding_mask.
// ---------------------------------------------------------------------------
__global__ __launch_bounds__(256) void prep_sin_kernel(
    const float* __restrict__ W1, const float* __restrict__ W2,
    const float* __restrict__ Wpfe, const float* __restrict__ Wproj,
    unsigned short* __restrict__ W1bf, unsigned short* __restrict__ W2bf,
    unsigned short* __restrict__ Wpfebf, unsigned short* __restrict__ Wprojbf,
    const float* __restrict__ time_step, const unsigned char* __restrict__ clean,
    const int* __restrict__ token, unsigned short* __restrict__ sin_bf,
    float* __restrict__ padout)
{
    const int blk = blockIdx.x;
    if (blk < 276) {
        const int i = blk * 256 + threadIdx.x;
        if (i >= 70656) return;
        const float* src; unsigned short* dst; int off;
        if (i < 4096)       { src = W1;    dst = W1bf;    off = i; }
        else if (i < 5120)  { src = W2;    dst = W2bf;    off = i - 4096; }
        else if (i < 37888) { src = Wpfe;  dst = Wpfebf;  off = i - 5120; }
        else                { src = Wproj; dst = Wprojbf; off = i - 37888; }
        const float4 v = ((const float4*)src)[off];
        ushort4 p; p.x = f2bf(v.x); p.y = f2bf(v.y); p.z = f2bf(v.z); p.w = f2bf(v.w);
        ((ushort4*)dst)[off] = p;
    } else {
        const int row = blk - 276;
        if (threadIdx.x == 0) padout[row] = (token[row] == 0) ? 1.0f : 0.0f;
        const float t = (clean[row] ? 0.0f : time_step[row]) * 1000.0f;
        for (int k = threadIdx.x; k < 512; k += 256) {
            const float f = __expf(-9.210340371976184f * (float)k * (1.0f / 512.0f));
            const float ang = t * f;
            sin_bf[(size_t)row * D_ + k]       = f2bf(__sinf(ang));
            sin_bf[(size_t)row * D_ + 512 + k] = f2bf(__cosf(ang));
        }
    }
}

// ---------------------------------------------------------------------------
// time-MLP GEMM body: A bf16 (M,Kd), B f32 (N,Kd) converted in staging.
// BM=32, BN=64, BK=64, 4 waves, register prefetch.
// smem layout: sA[32][72] ushort @0 (4608 B), sB[64][72] ushort @4608 (9216 B)
// ---------------------------------------------------------------------------
__device__ __forceinline__ void gemm_ts_body(
    char* smem, int m0, int n0,
    const unsigned short* __restrict__ A, const float* __restrict__ Bw,
    const float* __restrict__ bias, void* __restrict__ Cv,
    int N, int Kd, int act)
{
    unsigned short (*sA)[72] = (unsigned short(*)[72])smem;
    unsigned short (*sB)[72] = (unsigned short(*)[72])(smem + 4608);
    const int tid  = threadIdx.x;
    const int lane = tid & 63;
    const int wave = tid >> 6;
    const int l15  = lane & 15;
    const int quad = lane >> 4;
    const int mt   = wave & 1;
    const int np   = wave >> 1;

    // A: 32x64 bf16 = 256 uint4 chunks (1/thr); B: 64x64 f32 = 1024 float4 (4/thr)
    const int ar = tid >> 3, ac = (tid & 7) * 8;
    const int bc4 = (tid & 15) * 4;

    f32x4 acc[2];
#pragma unroll
    for (int t = 0; t < 2; ++t) acc[t] = (f32x4){0.f, 0.f, 0.f, 0.f};

    uint4 ra = *(const uint4*)&A[(size_t)(m0 + ar) * Kd + ac];
    float4 rbv[4];
#pragma unroll
    for (int c = 0; c < 4; ++c)
        rbv[c] = *(const float4*)&Bw[(size_t)(n0 + ((tid + c * 256) >> 4)) * Kd + bc4];

    for (int k0 = 0; k0 < Kd; k0 += 64) {
        *(uint4*)&sA[ar][ac] = ra;
#pragma unroll
        for (int c = 0; c < 4; ++c) {
            ushort4 p;
            p.x = f2bf(rbv[c].x); p.y = f2bf(rbv[c].y);
            p.z = f2bf(rbv[c].z); p.w = f2bf(rbv[c].w);
            *(ushort4*)&sB[(tid + c * 256) >> 4][bc4] = p;
        }
        __syncthreads();
        if (k0 + 64 < Kd) {
            ra = *(const uint4*)&A[(size_t)(m0 + ar) * Kd + k0 + 64 + ac];
#pragma unroll
            for (int c = 0; c < 4; ++c)
                rbv[c] = *(const float4*)&Bw[(size_t)(n0 + ((tid + c * 256) >> 4)) * Kd + k0 + 64 + bc4];
        }
#pragma unroll
        for (int kk = 0; kk < 64; kk += 32) {
            const bf16x8 av = *(const bf16x8*)&sA[mt * 16 + l15][kk + quad * 8];
#pragma unroll
            for (int t = 0; t < 2; ++t) {
                const bf16x8 bv = *(const bf16x8*)&sB[(np * 2 + t) * 16 + l15][kk + quad * 8];
                acc[t] = __builtin_amdgcn_mfma_f32_16x16x32_bf16(av, bv, acc[t], 0, 0, 0);
            }
        }
        __syncthreads();
    }
#pragma unroll
    for (int t = 0; t < 2; ++t) {
        const int nc = n0 + (np * 2 + t) * 16 + l15;
        const float bv = bias[nc];
#pragma unroll
        for (int r = 0; r < 4; ++r) {
            const int mr = m0 + mt * 16 + quad * 4 + r;
            float v = acc[t][r] + bv;
            if (act) {
                v = v / (1.0f + __expf(-v));
                ((unsigned short*)Cv)[(size_t)mr * N + nc] = f2bf(v);
            } else {
                ((float*)Cv)[(size_t)mr * N + nc] = v;
            }
        }
    }
}

// ---------------------------------------------------------------------------
// Edge body (R8 structure: one block per (b,i) row, 12 tiles, dbuf sEF,
// W1/W2 fragments in registers, coalesced pab lines).
// smem pool (34816 B): sEF@0 [2][32][136]us, sACT@17408 [32][136]us,
// sGab@26112 [32][33]f, sD@30336 [384]f, sRed@31872 [256]f,
// sYall@32896 [384]f, sPadCol@34432 [384]uc
// ---------------------------------------------------------------------------
__device__ __forceinline__ void edge_body(
    char* smem, int row,
    const int* __restrict__ token_id,
    const unsigned char* __restrict__ is_periodic,
    const float* __restrict__ pos,
    const unsigned char* __restrict__ adj,
    const int* __restrict__ nte,
    const float* __restrict__ gbf_means,
    const float* __restrict__ gbf_stds,
    const float* __restrict__ gbf_mul,
    const float* __restrict__ gbf_bias,
    const float* __restrict__ b1,
    const float* __restrict__ b2,
    const float* __restrict__ Wpos,
    const unsigned short* __restrict__ W1bf,
    const unsigned short* __restrict__ W2bf,
    unsigned short* __restrict__ pfe_bf,
    unsigned short* __restrict__ ef_bf,
    float* __restrict__ out_pab)
{
    const int b = row / L_;
    const int i = row - b * L_;
    const int tid = threadIdx.x;

    const int tok_i = token_id[row];
    if (tok_i == 0) {
        for (int idx = tid; idx < H_ * L_; idx += 256) {
            const int h = idx / L_;
            const int j = idx - h * L_;
            out_pab[((size_t)(b * H_ + h) * L_ + i) * L_ + j] = 0.0f;
        }
        if (tid < K_) {
            pfe_bf[(size_t)row * K_ + tid] = 0;
            ef_bf[(size_t)row * K_ + tid]  = 0;
        }
        return;
    }

    typedef unsigned short efbuf_t[32][136];
    efbuf_t* sEF = (efbuf_t*)smem;
    unsigned short (*sACT)[136] = (unsigned short(*)[136])(smem + 17408);
    float (*sGab)[33] = (float(*)[33])(smem + 26112);
    float* sD      = (float*)(smem + 30336);
    float* sRed    = (float*)(smem + 31872);
    float* sYall   = (float*)(smem + 32896);
    unsigned char* sPadCol = (unsigned char*)(smem + 34432);

    for (int j = tid; j < L_; j += 256)
        sPadCol[j] = (token_id[b * L_ + j] == 0) ? 1 : 0;

    const float px = pos[(size_t)row * 3 + 0];
    const float py = pos[(size_t)row * 3 + 1];
    const float pz = pos[(size_t)row * 3 + 2];
    for (int jg2 = tid; jg2 < L_; jg2 += 256) {
        const float dx = px - pos[(size_t)(b * L_ + jg2) * 3 + 0];
        const float dy = py - pos[(size_t)(b * L_ + jg2) * 3 + 1];
        const float dz = pz - pos[(size_t)(b * L_ + jg2) * 3 + 2];
        const float dist = sqrtf(fmaxf(dx * dx + dy * dy + dz * dz, 1e-12f));
        const size_t eoff = ((size_t)(b * L_ + i) * L_ + jg2) * 2;
        const int e0 = nte[eoff], e1 = nte[eoff + 1];
        sYall[jg2] = (gbf_mul[e0] + gbf_mul[e1]) * dist + (gbf_bias[e0] + gbf_bias[e1]);
    }

    const int lane = tid & 63;
    const int wave = tid >> 6;
    const int l15  = lane & 15;
    const int quad = lane >> 4;
    const int mt   = wave & 1;
    const int ntb  = (wave >> 1) * 4;
    float rb1[4];
#pragma unroll
    for (int nt = 0; nt < 4; ++nt) rb1[nt] = b1[(ntb + nt) * 16 + l15];
    const int hc = (wave >> 1) * 16 + l15;
    const float rb2 = b2[hc];
    bf16x8 w1f[4][4];
#pragma unroll
    for (int ks = 0; ks < 4; ++ks)
#pragma unroll
        for (int nt = 0; nt < 4; ++nt)
            w1f[ks][nt] = *(const bf16x8*)&W1bf[((ntb + nt) * 16 + l15) * K_ + ks * 32 + quad * 8];
    bf16x8 bv2[4];
#pragma unroll
    for (int ks = 0; ks < 4; ++ks)
        bv2[ks] = *(const bf16x8*)&W2bf[hc * K_ + ks * 32 + quad * 8];

    const int kg4 = (tid & 31) * 4;
    const int jg  = tid >> 5;
    const int jb  = jg * 4;
    float meanv[4], istdv[4], cKv[4];
#pragma unroll
    for (int c = 0; c < 4; ++c) {
        meanv[c] = gbf_means[kg4 + c];
        const float s = fabsf(gbf_stds[kg4 + c]) + 1e-5f;
        istdv[c] = 1.0f / s;
        cKv[c]   = INV_SQRT_2PI * istdv[c];
    }
    float efs[4] = {0.f, 0.f, 0.f, 0.f};

    __syncthreads();

#pragma unroll
    for (int jj = 0; jj < 4; ++jj) {
        const int j = jb + jj;
        const float y = sYall[j];
        const bool ok = !sPadCol[j];
        ushort4 p;
#pragma unroll
        for (int c = 0; c < 4; ++c) {
            const float a = (y - meanv[c]) * istdv[c];
            const float ef = __expf(-0.5f * a * a) * cKv[c];
            ((unsigned short*)&p)[c] = f2bf_rtz(ef);
            if (ok) efs[c] += ef;
        }
        *(ushort4*)&sEF[0][j][kg4] = p;
    }
    __syncthreads();

    for (int tile = 0; tile < L_ / 32; ++tile) {
        const int jt0 = tile * 32;
        const int cur = tile & 1, nxt = cur ^ 1;

        f32x4 acc1[4];
#pragma unroll
        for (int nt = 0; nt < 4; ++nt) acc1[nt] = (f32x4){0.f, 0.f, 0.f, 0.f};
#pragma unroll
        for (int ks = 0; ks < 4; ++ks) {
            const bf16x8 av = *(const bf16x8*)&sEF[cur][mt * 16 + l15][ks * 32 + quad * 8];
#pragma unroll
            for (int nt = 0; nt < 4; ++nt)
                acc1[nt] = __builtin_amdgcn_mfma_f32_16x16x32_bf16(av, w1f[ks][nt], acc1[nt], 0, 0, 0);
        }

        if (tile + 1 < L_ / 32) {
            const int jn0 = jt0 + 32;
#pragma unroll
            for (int jj = 0; jj < 4; ++jj) {
                const int j = jb + jj;
                const float y = sYall[jn0 + j];
                const bool ok = !sPadCol[jn0 + j];
                ushort4 p;
#pragma unroll
                for (int c = 0; c < 4; ++c) {
                    const float a = (y - meanv[c]) * istdv[c];
                    const float ef = __expf(-0.5f * a * a) * cKv[c];
                    ((unsigned short*)&p)[c] = f2bf_rtz(ef);
                    if (ok) efs[c] += ef;
                }
                *(ushort4*)&sEF[nxt][j][kg4] = p;
            }
        }

#pragma unroll
        for (int nt = 0; nt < 4; ++nt) {
            const int kkc = (ntb + nt) * 16 + l15;
#pragma unroll
            for (int r = 0; r < 4; ++r) {
                const float v = gelu_tanh(acc1[nt][r] + rb1[nt]);
                sACT[mt * 16 + quad * 4 + r][kkc] = f2bf_rtz(v);
            }
        }
        __syncthreads();   // A

        f32x4 acc2 = (f32x4){0.f, 0.f, 0.f, 0.f};
#pragma unroll
        for (int ks = 0; ks < 4; ++ks) {
            const bf16x8 av = *(const bf16x8*)&sACT[mt * 16 + l15][ks * 32 + quad * 8];
            acc2 = __builtin_amdgcn_mfma_f32_16x16x32_bf16(av, bv2[ks], acc2, 0, 0, 0);
        }
        const int jl0 = mt * 16 + quad * 4;
#pragma unroll
        for (int r = 0; r < 4; ++r) sGab[jl0 + r][hc] = acc2[r] + rb2;
        __syncthreads();   // B

        {
            const int h = tid >> 3, f = tid & 7;
            const int jb2 = f * 4;
            float4 st;
#pragma unroll
            for (int r = 0; r < 4; ++r) {
                float v = finitize(sGab[jb2 + r][h]);
                if (sPadCol[jt0 + jb2 + r]) v = NEG_BIG;
                ((float*)&st)[r] = v;
            }
            *(float4*)&out_pab[((size_t)(b * H_ + h) * L_ + i) * L_ + jt0 + jb2] = st;
        }
        if (tid < 32) {
            float s = 0.0f;
#pragma unroll
            for (int h = 0; h < 32; ++h) s += sGab[tid][h];
            sD[jt0 + tid] = s;
        }
    }

    {
        float* efScr = (float*)sACT;
#pragma unroll
        for (int c = 0; c < 4; ++c) efScr[jg * 128 + kg4 + c] = efs[c];
    }
    __syncthreads();
    if (tid < 128) {
        const float* efScr = (const float*)sACT;
        float s = 0.0f;
#pragma unroll
        for (int g = 0; g < 8; ++g) s += efScr[g * 128 + tid];
        ef_bf[(size_t)row * K_ + tid] = f2bf(s);
    }
    __syncthreads();

    const bool molecule = (tok_i <= 129) && (is_periodic[b] == 0);
    float lmax = -INFINITY;
    for (int j = tid; j < L_; j += 256) {
        const bool colpad = sPadCol[j] != 0;
        const bool adj_eff = (adj[((size_t)(b * L_ + i)) * L_ + j] != 0) || (!molecule);
        const float dv = (colpad || !adj_eff) ? MINV : sD[j];
        const float s = dv * SCALING_;
        sD[j] = s;
        lmax = fmaxf(lmax, s);
    }
#pragma unroll
    for (int off = 32; off > 0; off >>= 1) lmax = fmaxf(lmax, __shfl_xor(lmax, off));
    if (lane == 0) sRed[wave] = lmax;
    __syncthreads();
    const float smax = fmaxf(fmaxf(sRed[0], sRed[1]), fmaxf(sRed[2], sRed[3]));
    float lsum = 0.0f;
    for (int j = tid; j < L_; j += 256) {
        const float e = __expf(sD[j] - smax);
        sD[j] = e;
        lsum += e;
    }
#pragma unroll
    for (int off = 32; off > 0; off >>= 1) lsum += __shfl_xor(lsum, off);
    if (lane == 0) sRed[4 + wave] = lsum;
    __syncthreads();
    const float inv = 1.0f / (sRed[4] + sRed[5] + sRed[6] + sRed[7]);

    float a0 = 0.f, a1 = 0.f, a2 = 0.f;
    for (int j = tid; j < L_; j += 256) {
        if (!sPadCol[j]) {
            const float e = sD[j];
            a0 += e * pos[(size_t)(b * L_ + j) * 3 + 0];
            a1 += e * pos[(size_t)(b * L_ + j) * 3 + 1];
            a2 += e * pos[(size_t)(b * L_ + j) * 3 + 2];
        }
    }
#pragma unroll
    for (int off = 32; off > 0; off >>= 1) {
        a0 += __shfl_xor(a0, off);
        a1 += __shfl_xor(a1, off);
        a2 += __shfl_xor(a2, off);
    }
    if (lane == 0) { sRed[8 + wave] = a0; sRed[12 + wave] = a1; sRed[16 + wave] = a2; }
    __syncthreads();
    if (tid < 128) {
        const float m0 = sRed[8] + sRed[9] + sRed[10] + sRed[11];
        const float m1 = sRed[12] + sRed[13] + sRed[14] + sRed[15];
        const float m2 = sRed[16] + sRed[17] + sRed[18] + sRed[19];
        const float w0 = Wpos[tid * 3 + 0], w1 = Wpos[tid * 3 + 1], w2 = Wpos[tid * 3 + 2];
        pfe_bf[(size_t)row * K_ + tid] = f2bf((m0 * w0 + m1 * w1 + m2 * w2) * inv);
    }
}

// ---------------------------------------------------------------------------
// Fat kernel: blocks [0,768) = edge rows; [768,1152) = time-MLP layer 1
// (independent stages co-scheduled to fill the machine).
// ---------------------------------------------------------------------------
__global__ __launch_bounds__(256, 3) void edge_ts1(
    const int* __restrict__ token_id,
    const unsigned char* __restrict__ is_periodic,
    const float* __restrict__ pos,
    const unsigned char* __restrict__ adj,
    const int* __restrict__ nte,
    const float* __restrict__ gbf_means,
    const float* __restrict__ gbf_stds,
    const float* __restrict__ gbf_mul,
    const float* __restrict__ gbf_bias,
    const float* __restrict__ b1,
    const float* __restrict__ b2,
    const float* __restrict__ Wpos,
    const unsigned short* __restrict__ W1bf,
    const unsigned short* __restrict__ W2bf,
    unsigned short* __restrict__ pfe_bf,
    unsigned short* __restrict__ ef_bf,
    float* __restrict__ out_pab,
    const unsigned short* __restrict__ sin_bf,
    const float* __restrict__ Wt1,
    const float* __restrict__ bt1,
    unsigned short* __restrict__ h1_bf)
{
    __shared__ __align__(16) char smem[34816];
    const int bx = blockIdx.x;
    if (bx < B_ * L_) {
        edge_body(smem, bx, token_id, is_periodic, pos, adj, nte,
                  gbf_means, gbf_stds, gbf_mul, gbf_bias, b1, b2, Wpos,
                  W1bf, W2bf, pfe_bf, ef_bf, out_pab);
    } else {
        const int tsb = bx - B_ * L_;          // [0,384): 24 m-blocks x 16 n-blocks
        const int m0 = (tsb >> 4) * 32;
        const int n0 = (tsb & 15) * 64;
        gemm_ts_body(smem, m0, n0, sin_bf, Wt1, bt1, (void*)h1_bf, D_, D_, 1);
    }
}

// ---------------------------------------------------------------------------
// Standalone time-MLP layer 2 (f32 out to out_te). grid (16,24).
// ---------------------------------------------------------------------------
__global__ __launch_bounds__(256) void gemm_ts2(const unsigned short* __restrict__ A,
                                                const float* __restrict__ Bw,
                                                const float* __restrict__ bias,
                                                float* __restrict__ C)
{
    __shared__ __align__(16) char smem[13824];
    gemm_ts_body(smem, blockIdx.y * 32, blockIdx.x * 64, A, Bw, bias, (void*)C,
                 D_, D_, 0);
}

// ---------------------------------------------------------------------------
// pos_embedding MFMA GEMM fused with combine. BM=32, BN=64, grid (16, 24).
// ---------------------------------------------------------------------------
__global__ __launch_bounds__(256) void pe_gemm(const unsigned short* __restrict__ pfe_bf,
                                               const unsigned short* __restrict__ ef_bf,
                                               const unsigned short* __restrict__ Wpfebf,
                                               const unsigned short* __restrict__ Wprojbf,
                                               const float* __restrict__ bproj,
                                               const int* __restrict__ token,
                                               const float* __restrict__ embed_w,
                                               const float* __restrict__ te,
                                               float* __restrict__ outPE,
                                               float* __restrict__ outX)
{
    __shared__ unsigned short sA[32][136];
    __shared__ unsigned short sB[64][136];
    const int tid  = threadIdx.x;
    const int lane = tid & 63;
    const int wave = tid >> 6;
    const int l15  = lane & 15;
    const int quad = lane >> 4;
    const int mt   = wave & 1;
    const int np   = wave >> 1;
    const int m0 = blockIdx.y * 32, n0 = blockIdx.x * 64;

    f32x4 acc[2];
#pragma unroll
    for (int t = 0; t < 2; ++t) acc[t] = (f32x4){0.f, 0.f, 0.f, 0.f};

    for (int phase = 0; phase < 2; ++phase) {
        const unsigned short* Ap = phase ? ef_bf : pfe_bf;
        const unsigned short* Bp = phase ? Wprojbf : Wpfebf;
#pragma unroll
        for (int e = tid; e < 512; e += 256) {
            const int r = e >> 4, c8 = (e & 15) * 8;
            *(uint4*)&sA[r][c8] = *(const uint4*)&Ap[(size_t)(m0 + r) * K_ + c8];
        }
#pragma unroll
        for (int e = tid; e < 1024; e += 256) {
            const int r = e >> 4, c8 = (e & 15) * 8;
            *(uint4*)&sB[r][c8] = *(const uint4*)&Bp[(size_t)(n0 + r) * K_ + c8];
        }
        __syncthreads();
#pragma unroll
        for (int ks = 0; ks < 4; ++ks) {
            const bf16x8 av = *(const bf16x8*)&sA[mt * 16 + l15][ks * 32 + quad * 8];
#pragma unroll
            for (int t = 0; t < 2; ++t) {
                const bf16x8 bv = *(const bf16x8*)&sB[(np * 2 + t) * 16 + l15][ks * 32 + quad * 8];
                acc[t] = __builtin_amdgcn_mfma_f32_16x16x32_bf16(av, bv, acc[t], 0, 0, 0);
            }
        }
        __syncthreads();
    }
#pragma unroll
    for (int t = 0; t < 2; ++t) {
        const int nc = n0 + (np * 2 + t) * 16 + l15;
        const float bv = bproj[nc];
#pragma unroll
        for (int r = 0; r < 4; ++r) {
            const int mr = m0 + mt * 16 + quad * 4 + r;
            const int tok = token[mr];
            const float pe = (tok == 0) ? 0.0f : (acc[t][r] + bv);
            outPE[(size_t)mr * D_ + nc] = pe;
            outX[(size_t)mr * D_ + nc] = embed_w[(size_t)tok * D_ + nc]
                                       + te[(size_t)mr * D_ + nc] + pe;
        }
    }
}

// ---------------------------------------------------------------------------
extern "C" void kernel_launch(void* const* d_in, const int* in_sizes, int n_in,
                              void* d_out, int out_size, void* d_ws, size_t ws_size,
                              hipStream_t stream) {
    const int*           token_id    = (const int*)d_in[0];
    const unsigned char* is_periodic = (const unsigned char*)d_in[1];
    const float*         pos         = (const float*)d_in[2];
    const unsigned char* adj         = (const unsigned char*)d_in[3];
    const int*           nte         = (const int*)d_in[4];
    const float*         time_step   = (const float*)d_in[5];
    const unsigned char* clean_mask  = (const unsigned char*)d_in[6];
    const float*         embed_w     = (const float*)d_in[7];
    const float*         Wpos        = (const float*)d_in[8];
    const float*         Wpfe        = (const float*)d_in[9];
    const float*         gbf_means   = (const float*)d_in[10];
    const float*         gbf_stds    = (const float*)d_in[11];
    const float*         gbf_mul     = (const float*)d_in[12];
    const float*         gbf_bias    = (const float*)d_in[13];
    const float*         W1          = (const float*)d_in[14];
    const float*         b1          = (const float*)d_in[15];
    const float*         W2          = (const float*)d_in[16];
    const float*         b2          = (const float*)d_in[17];
    const float*         Wproj       = (const float*)d_in[18];
    const float*         bproj       = (const float*)d_in[19];
    const float*         Wt1         = (const float*)d_in[20];
    const float*         bt1         = (const float*)d_in[21];
    const float*         Wt2         = (const float*)d_in[22];
    const float*         bt2         = (const float*)d_in[23];

    float* out = (float*)d_out;
    float* out_x   = out;                 // (B,L,D)
    float* out_pad = out + 786432;        // (B,L)
    float* out_te  = out + 787200;        // (B,L,D)
    float* out_pab = out + 1573632;       // (B,H,L,L)
    float* out_pe  = out + 11010816;      // (B,L,D)

    // workspace (ushort units), ~4.1 MB
    unsigned short* wsu = (unsigned short*)d_ws;
    unsigned short* W1bf    = wsu;                 // 16384
    unsigned short* W2bf    = wsu + 16384;         // 4096
    unsigned short* Wpfebf  = wsu + 20480;         // 131072
    unsigned short* Wprojbf = wsu + 151552;        // 131072
    unsigned short* sin_bf  = wsu + 282624;        // 786432
    unsigned short* h1_bf   = wsu + 1069056;       // 786432
    unsigned short* pfe_bf  = wsu + 1855488;       // 98304
    unsigned short* ef_bf   = wsu + 1953792;       // 98304

    prep_sin_kernel<<<dim3(1044), dim3(256), 0, stream>>>(
        W1, W2, Wpfe, Wproj, W1bf, W2bf, Wpfebf, Wprojbf,
        time_step, clean_mask, token_id, sin_bf, out_pad);
    edge_ts1<<<dim3(B_ * L_ + 384), dim3(256), 0, stream>>>(
        token_id, is_periodic, pos, adj, nte, gbf_means, gbf_stds, gbf_mul, gbf_bias,
        b1, b2, Wpos, W1bf, W2bf, pfe_bf, ef_bf, out_pab,
        sin_bf, Wt1, bt1, h1_bf);
    gemm_ts2<<<dim3(16, 24), dim3(256), 0, stream>>>(h1_bf, Wt2, bt2, out_te);
    pe_gemm<<<dim3(16, 24), dim3(256), 0, stream>>>(pfe_bf, ef_bf, Wpfebf, Wprojbf,
                                                    bproj, token_id, embed_w, out_te,
                                                    out_pe, out_x);
}

// Round 11
// 188.077 us; speedup vs baseline: 1.4066x; 1.0132x over previous
//
#include <hip/hip_runtime.h>
#include <stddef.h>

#define B_ 2
#define L_ 384
#define D_ 1024
#define K_ 128
#define H_ 32

#define MINV (-3.402823466e38f)
// Exported -inf sentinel: must stay FINITE after bf16 rounding (bf16 max ~3.39e38).
#define NEG_BIG (-1.0e38f)
#define SCALING_ 0.08838834764831845f
#define INV_SQRT_2PI 0.3989422804014327f

typedef __attribute__((ext_vector_type(8))) short bf16x8;
typedef __attribute__((ext_vector_type(4))) float f32x4;

__device__ __forceinline__ float finitize(float x) {
    return fminf(fmaxf(x, -1.0e38f), 1.0e38f);
}
__device__ __forceinline__ unsigned short f2bf(float x) {
    unsigned int u = __float_as_uint(x);
    u += 0x7FFFu + ((u >> 16) & 1u);
    return (unsigned short)(u >> 16);
}
__device__ __forceinline__ unsigned short f2bf_rtz(float x) {
    return (unsigned short)(__float_as_uint(x) >> 16);
}
// tanh-form gelu: max abs err ~3e-4, 1 exp + 1 rcp
__device__ __forceinline__ float gelu_tanh(float x) {
    const float x2 = x * x;
    const float z = x * fmaf(0.0356774081f, x2, 0.7978845608f);
    const float e = __expf(2.0f * z);
    const float t = fmaf(-2.0f, __builtin_amdgcn_rcpf(e + 1.0f), 1.0f);
    const float hx = 0.5f * x;
    return fmaf(hx, t, hx);
}

// ---------------------------------------------------------------------------
// prep+sin fused: blocks [0,276) convert W1/W2/Wpfe/Wproj f32->bf16
// (70656 float4 chunks); blocks [276,1044) sinusoidal features + padding_mask.
// ---------------------------------------------------------------------------
__global__ __launch_bounds__(256) void prep_sin_kernel(
    const float* __restrict__ W1, const float* __restrict__ W2,
    const float* __restrict__ Wpfe, const float* __restrict__ Wproj,
    unsigned short* __restrict__ W1bf, unsigned short* __restrict__ W2bf,
    unsigned short* __restrict__ Wpfebf, unsigned short* __restrict__ Wprojbf,
    const float* __restrict__ time_step, const unsigned char* __restrict__ clean,
    const int* __restrict__ token, unsigned short* __restrict__ sin_bf,
    float* __restrict__ padout)
{
    const int blk = blockIdx.x;
    if (blk < 276) {
        const int i = blk * 256 + threadIdx.x;
        if (i >= 70656) return;
        const float* src; unsigned short* dst; int off;
        if (i < 4096)       { src = W1;    dst = W1bf;    off = i; }
        else if (i < 5120)  { src = W2;    dst = W2bf;    off = i - 4096; }
        else if (i < 37888) { src = Wpfe;  dst = Wpfebf;  off = i - 5120; }
        else                { src = Wproj; dst = Wprojbf; off = i - 37888; }
        const float4 v = ((const float4*)src)[off];
        ushort4 p; p.x = f2bf(v.x); p.y = f2bf(v.y); p.z = f2bf(v.z); p.w = f2bf(v.w);
        ((ushort4*)dst)[off] = p;
    } else {
        const int row = blk - 276;
        if (threadIdx.x == 0) padout[row] = (token[row] == 0) ? 1.0f : 0.0f;
        const float t = (clean[row] ? 0.0f : time_step[row]) * 1000.0f;
        for (int k = threadIdx.x; k < 512; k += 256) {
            const float f = __expf(-9.210340371976184f * (float)k * (1.0f / 512.0f));
            const float ang = t * f;
            sin_bf[(size_t)row * D_ + k]       = f2bf(__sinf(ang));
            sin_bf[(size_t)row * D_ + 512 + k] = f2bf(__cosf(ang));
        }
    }
}

// ---------------------------------------------------------------------------
// time-MLP GEMM body: A bf16 (M,Kd), B f32 (N,Kd) converted in staging.
// BM=32, BN=64, BK=64, 4 waves, register prefetch. acc returned to caller
// (accOut) when Cv==nullptr; otherwise epilogue writes Cv (act as before).
// smem: sA[32][72] us @0 (4608 B), sB[64][72] us @4608 (9216 B) = 13824 B
// ---------------------------------------------------------------------------
__device__ __forceinline__ void gemm_ts_body(
    char* smem, int m0, int n0,
    const unsigned short* __restrict__ A, const float* __restrict__ Bw,
    const float* __restrict__ bias, void* __restrict__ Cv,
    int N, int Kd, int act, f32x4* accOut)
{
    unsigned short (*sA)[72] = (unsigned short(*)[72])smem;
    unsigned short (*sB)[72] = (unsigned short(*)[72])(smem + 4608);
    const int tid  = threadIdx.x;
    const int lane = tid & 63;
    const int wave = tid >> 6;
    const int l15  = lane & 15;
    const int quad = lane >> 4;
    const int mt   = wave & 1;
    const int np   = wave >> 1;

    const int ar = tid >> 3, ac = (tid & 7) * 8;
    const int bc4 = (tid & 15) * 4;

    f32x4 acc[2];
#pragma unroll
    for (int t = 0; t < 2; ++t) acc[t] = (f32x4){0.f, 0.f, 0.f, 0.f};

    uint4 ra = *(const uint4*)&A[(size_t)(m0 + ar) * Kd + ac];
    float4 rbv[4];
#pragma unroll
    for (int c = 0; c < 4; ++c)
        rbv[c] = *(const float4*)&Bw[(size_t)(n0 + ((tid + c * 256) >> 4)) * Kd + bc4];

    for (int k0 = 0; k0 < Kd; k0 += 64) {
        *(uint4*)&sA[ar][ac] = ra;
#pragma unroll
        for (int c = 0; c < 4; ++c) {
            ushort4 p;
            p.x = f2bf(rbv[c].x); p.y = f2bf(rbv[c].y);
            p.z = f2bf(rbv[c].z); p.w = f2bf(rbv[c].w);
            *(ushort4*)&sB[(tid + c * 256) >> 4][bc4] = p;
        }
        __syncthreads();
        if (k0 + 64 < Kd) {
            ra = *(const uint4*)&A[(size_t)(m0 + ar) * Kd + k0 + 64 + ac];
#pragma unroll
            for (int c = 0; c < 4; ++c)
                rbv[c] = *(const float4*)&Bw[(size_t)(n0 + ((tid + c * 256) >> 4)) * Kd + k0 + 64 + bc4];
        }
#pragma unroll
        for (int kk = 0; kk < 64; kk += 32) {
            const bf16x8 av = *(const bf16x8*)&sA[mt * 16 + l15][kk + quad * 8];
#pragma unroll
            for (int t = 0; t < 2; ++t) {
                const bf16x8 bv = *(const bf16x8*)&sB[(np * 2 + t) * 16 + l15][kk + quad * 8];
                acc[t] = __builtin_amdgcn_mfma_f32_16x16x32_bf16(av, bv, acc[t], 0, 0, 0);
            }
        }
        __syncthreads();
    }
    if (accOut) {
        accOut[0] = acc[0];
        accOut[1] = acc[1];
        return;
    }
#pragma unroll
    for (int t = 0; t < 2; ++t) {
        const int nc = n0 + (np * 2 + t) * 16 + l15;
        const float bv = bias[nc];
#pragma unroll
        for (int r = 0; r < 4; ++r) {
            const int mr = m0 + mt * 16 + quad * 4 + r;
            float v = acc[t][r] + bv;
            if (act) {
                v = v / (1.0f + __expf(-v));
                ((unsigned short*)Cv)[(size_t)mr * N + nc] = f2bf(v);
            } else {
                ((float*)Cv)[(size_t)mr * N + nc] = v;
            }
        }
    }
}

// ---------------------------------------------------------------------------
// Edge body (R8 structure, known-good).
// smem pool (34816 B): sEF@0 [2][32][136]us, sACT@17408 [32][136]us,
// sGab@26112 [32][33]f, sD@30336 [384]f, sRed@31872 [256]f,
// sYall@32896 [384]f, sPadCol@34432 [384]uc
// ---------------------------------------------------------------------------
__device__ __forceinline__ void edge_body(
    char* smem, int row,
    const int* __restrict__ token_id,
    const unsigned char* __restrict__ is_periodic,
    const float* __restrict__ pos,
    const unsigned char* __restrict__ adj,
    const int* __restrict__ nte,
    const float* __restrict__ gbf_means,
    const float* __restrict__ gbf_stds,
    const float* __restrict__ gbf_mul,
    const float* __restrict__ gbf_bias,
    const float* __restrict__ b1,
    const float* __restrict__ b2,
    const float* __restrict__ Wpos,
    const unsigned short* __restrict__ W1bf,
    const unsigned short* __restrict__ W2bf,
    unsigned short* __restrict__ pfe_bf,
    unsigned short* __restrict__ ef_bf,
    float* __restrict__ out_pab)
{
    const int b = row / L_;
    const int i = row - b * L_;
    const int tid = threadIdx.x;

    const int tok_i = token_id[row];
    if (tok_i == 0) {
        for (int idx = tid; idx < H_ * L_; idx += 256) {
            const int h = idx / L_;
            const int j = idx - h * L_;
            out_pab[((size_t)(b * H_ + h) * L_ + i) * L_ + j] = 0.0f;
        }
        if (tid < K_) {
            pfe_bf[(size_t)row * K_ + tid] = 0;
            ef_bf[(size_t)row * K_ + tid]  = 0;
        }
        return;
    }

    typedef unsigned short efbuf_t[32][136];
    efbuf_t* sEF = (efbuf_t*)smem;
    unsigned short (*sACT)[136] = (unsigned short(*)[136])(smem + 17408);
    float (*sGab)[33] = (float(*)[33])(smem + 26112);
    float* sD      = (float*)(smem + 30336);
    float* sRed    = (float*)(smem + 31872);
    float* sYall   = (float*)(smem + 32896);
    unsigned char* sPadCol = (unsigned char*)(smem + 34432);

    for (int j = tid; j < L_; j += 256)
        sPadCol[j] = (token_id[b * L_ + j] == 0) ? 1 : 0;

    const float px = pos[(size_t)row * 3 + 0];
    const float py = pos[(size_t)row * 3 + 1];
    const float pz = pos[(size_t)row * 3 + 2];
    for (int jg2 = tid; jg2 < L_; jg2 += 256) {
        const float dx = px - pos[(size_t)(b * L_ + jg2) * 3 + 0];
        const float dy = py - pos[(size_t)(b * L_ + jg2) * 3 + 1];
        const float dz = pz - pos[(size_t)(b * L_ + jg2) * 3 + 2];
        const float dist = sqrtf(fmaxf(dx * dx + dy * dy + dz * dz, 1e-12f));
        const size_t eoff = ((size_t)(b * L_ + i) * L_ + jg2) * 2;
        const int e0 = nte[eoff], e1 = nte[eoff + 1];
        sYall[jg2] = (gbf_mul[e0] + gbf_mul[e1]) * dist + (gbf_bias[e0] + gbf_bias[e1]);
    }

    const int lane = tid & 63;
    const int wave = tid >> 6;
    const int l15  = lane & 15;
    const int quad = lane >> 4;
    const int mt   = wave & 1;
    const int ntb  = (wave >> 1) * 4;
    float rb1[4];
#pragma unroll
    for (int nt = 0; nt < 4; ++nt) rb1[nt] = b1[(ntb + nt) * 16 + l15];
    const int hc = (wave >> 1) * 16 + l15;
    const float rb2 = b2[hc];
    bf16x8 w1f[4][4];
#pragma unroll
    for (int ks = 0; ks < 4; ++ks)
#pragma unroll
        for (int nt = 0; nt < 4; ++nt)
            w1f[ks][nt] = *(const bf16x8*)&W1bf[((ntb + nt) * 16 + l15) * K_ + ks * 32 + quad * 8];
    bf16x8 bv2[4];
#pragma unroll
    for (int ks = 0; ks < 4; ++ks)
        bv2[ks] = *(const bf16x8*)&W2bf[hc * K_ + ks * 32 + quad * 8];

    const int kg4 = (tid & 31) * 4;
    const int jg  = tid >> 5;
    const int jb  = jg * 4;
    float meanv[4], istdv[4], cKv[4];
#pragma unroll
    for (int c = 0; c < 4; ++c) {
        meanv[c] = gbf_means[kg4 + c];
        const float s = fabsf(gbf_stds[kg4 + c]) + 1e-5f;
        istdv[c] = 1.0f / s;
        cKv[c]   = INV_SQRT_2PI * istdv[c];
    }
    float efs[4] = {0.f, 0.f, 0.f, 0.f};

    __syncthreads();

#pragma unroll
    for (int jj = 0; jj < 4; ++jj) {
        const int j = jb + jj;
        const float y = sYall[j];
        const bool ok = !sPadCol[j];
        ushort4 p;
#pragma unroll
        for (int c = 0; c < 4; ++c) {
            const float a = (y - meanv[c]) * istdv[c];
            const float ef = __expf(-0.5f * a * a) * cKv[c];
            ((unsigned short*)&p)[c] = f2bf_rtz(ef);
            if (ok) efs[c] += ef;
        }
        *(ushort4*)&sEF[0][j][kg4] = p;
    }
    __syncthreads();

    for (int tile = 0; tile < L_ / 32; ++tile) {
        const int jt0 = tile * 32;
        const int cur = tile & 1, nxt = cur ^ 1;

        f32x4 acc1[4];
#pragma unroll
        for (int nt = 0; nt < 4; ++nt) acc1[nt] = (f32x4){0.f, 0.f, 0.f, 0.f};
#pragma unroll
        for (int ks = 0; ks < 4; ++ks) {
            const bf16x8 av = *(const bf16x8*)&sEF[cur][mt * 16 + l15][ks * 32 + quad * 8];
#pragma unroll
            for (int nt = 0; nt < 4; ++nt)
                acc1[nt] = __builtin_amdgcn_mfma_f32_16x16x32_bf16(av, w1f[ks][nt], acc1[nt], 0, 0, 0);
        }

        if (tile + 1 < L_ / 32) {
            const int jn0 = jt0 + 32;
#pragma unroll
            for (int jj = 0; jj < 4; ++jj) {
                const int j = jb + jj;
                const float y = sYall[jn0 + j];
                const bool ok = !sPadCol[jn0 + j];
                ushort4 p;
#pragma unroll
                for (int c = 0; c < 4; ++c) {
                    const float a = (y - meanv[c]) * istdv[c];
                    const float ef = __expf(-0.5f * a * a) * cKv[c];
                    ((unsigned short*)&p)[c] = f2bf_rtz(ef);
                    if (ok) efs[c] += ef;
                }
                *(ushort4*)&sEF[nxt][j][kg4] = p;
            }
        }

#pragma unroll
        for (int nt = 0; nt < 4; ++nt) {
            const int kkc = (ntb + nt) * 16 + l15;
#pragma unroll
            for (int r = 0; r < 4; ++r) {
                const float v = gelu_tanh(acc1[nt][r] + rb1[nt]);
                sACT[mt * 16 + quad * 4 + r][kkc] = f2bf_rtz(v);
            }
        }
        __syncthreads();   // A

        f32x4 acc2 = (f32x4){0.f, 0.f, 0.f, 0.f};
#pragma unroll
        for (int ks = 0; ks < 4; ++ks) {
            const bf16x8 av = *(const bf16x8*)&sACT[mt * 16 + l15][ks * 32 + quad * 8];
            acc2 = __builtin_amdgcn_mfma_f32_16x16x32_bf16(av, bv2[ks], acc2, 0, 0, 0);
        }
        const int jl0 = mt * 16 + quad * 4;
#pragma unroll
        for (int r = 0; r < 4; ++r) sGab[jl0 + r][hc] = acc2[r] + rb2;
        __syncthreads();   // B

        {
            const int h = tid >> 3, f = tid & 7;
            const int jb2 = f * 4;
            float4 st;
#pragma unroll
            for (int r = 0; r < 4; ++r) {
                float v = finitize(sGab[jb2 + r][h]);
                if (sPadCol[jt0 + jb2 + r]) v = NEG_BIG;
                ((float*)&st)[r] = v;
            }
            *(float4*)&out_pab[((size_t)(b * H_ + h) * L_ + i) * L_ + jt0 + jb2] = st;
        }
        if (tid < 32) {
            float s = 0.0f;
#pragma unroll
            for (int h = 0; h < 32; ++h) s += sGab[tid][h];
            sD[jt0 + tid] = s;
        }
    }

    {
        float* efScr = (float*)sACT;
#pragma unroll
        for (int c = 0; c < 4; ++c) efScr[jg * 128 + kg4 + c] = efs[c];
    }
    __syncthreads();
    if (tid < 128) {
        const float* efScr = (const float*)sACT;
        float s = 0.0f;
#pragma unroll
        for (int g = 0; g < 8; ++g) s += efScr[g * 128 + tid];
        ef_bf[(size_t)row * K_ + tid] = f2bf(s);
    }
    __syncthreads();

    const bool molecule = (tok_i <= 129) && (is_periodic[b] == 0);
    float lmax = -INFINITY;
    for (int j = tid; j < L_; j += 256) {
        const bool colpad = sPadCol[j] != 0;
        const bool adj_eff = (adj[((size_t)(b * L_ + i)) * L_ + j] != 0) || (!molecule);
        const float dv = (colpad || !adj_eff) ? MINV : sD[j];
        const float s = dv * SCALING_;
        sD[j] = s;
        lmax = fmaxf(lmax, s);
    }
#pragma unroll
    for (int off = 32; off > 0; off >>= 1) lmax = fmaxf(lmax, __shfl_xor(lmax, off));
    if (lane == 0) sRed[wave] = lmax;
    __syncthreads();
    const float smax = fmaxf(fmaxf(sRed[0], sRed[1]), fmaxf(sRed[2], sRed[3]));
    float lsum = 0.0f;
    for (int j = tid; j < L_; j += 256) {
        const float e = __expf(sD[j] - smax);
        sD[j] = e;
        lsum += e;
    }
#pragma unroll
    for (int off = 32; off > 0; off >>= 1) lsum += __shfl_xor(lsum, off);
    if (lane == 0) sRed[4 + wave] = lsum;
    __syncthreads();
    const float inv = 1.0f / (sRed[4] + sRed[5] + sRed[6] + sRed[7]);

    float a0 = 0.f, a1 = 0.f, a2 = 0.f;
    for (int j = tid; j < L_; j += 256) {
        if (!sPadCol[j]) {
            const float e = sD[j];
            a0 += e * pos[(size_t)(b * L_ + j) * 3 + 0];
            a1 += e * pos[(size_t)(b * L_ + j) * 3 + 1];
            a2 += e * pos[(size_t)(b * L_ + j) * 3 + 2];
        }
    }
#pragma unroll
    for (int off = 32; off > 0; off >>= 1) {
        a0 += __shfl_xor(a0, off);
        a1 += __shfl_xor(a1, off);
        a2 += __shfl_xor(a2, off);
    }
    if (lane == 0) { sRed[8 + wave] = a0; sRed[12 + wave] = a1; sRed[16 + wave] = a2; }
    __syncthreads();
    if (tid < 128) {
        const float m0 = sRed[8] + sRed[9] + sRed[10] + sRed[11];
        const float m1 = sRed[12] + sRed[13] + sRed[14] + sRed[15];
        const float m2 = sRed[16] + sRed[17] + sRed[18] + sRed[19];
        const float w0 = Wpos[tid * 3 + 0], w1 = Wpos[tid * 3 + 1], w2 = Wpos[tid * 3 + 2];
        pfe_bf[(size_t)row * K_ + tid] = f2bf((m0 * w0 + m1 * w1 + m2 * w2) * inv);
    }
}

// ---------------------------------------------------------------------------
// Fat kernel: blocks [0,768) = edge rows; [768,1152) = time-MLP layer 1.
// ---------------------------------------------------------------------------
__global__ __launch_bounds__(256, 3) void edge_ts1(
    const int* __restrict__ token_id,
    const unsigned char* __restrict__ is_periodic,
    const float* __restrict__ pos,
    const unsigned char* __restrict__ adj,
    const int* __restrict__ nte,
    const float* __restrict__ gbf_means,
    const float* __restrict__ gbf_stds,
    const float* __restrict__ gbf_mul,
    const float* __restrict__ gbf_bias,
    const float* __restrict__ b1,
    const float* __restrict__ b2,
    const float* __restrict__ Wpos,
    const unsigned short* __restrict__ W1bf,
    const unsigned short* __restrict__ W2bf,
    unsigned short* __restrict__ pfe_bf,
    unsigned short* __restrict__ ef_bf,
    float* __restrict__ out_pab,
    const unsigned short* __restrict__ sin_bf,
    const float* __restrict__ Wt1,
    const float* __restrict__ bt1,
    unsigned short* __restrict__ h1_bf)
{
    __shared__ __align__(16) char smem[34816];
    const int bx = blockIdx.x;
    if (bx < B_ * L_) {
        edge_body(smem, bx, token_id, is_periodic, pos, adj, nte,
                  gbf_means, gbf_stds, gbf_mul, gbf_bias, b1, b2, Wpos,
                  W1bf, W2bf, pfe_bf, ef_bf, out_pab);
    } else {
        const int tsb = bx - B_ * L_;          // [0,384): 24 m-blocks x 16 n-blocks
        const int m0 = (tsb >> 4) * 32;
        const int n0 = (tsb & 15) * 64;
        gemm_ts_body(smem, m0, n0, sin_bf, Wt1, bt1, (void*)h1_bf, D_, D_, 1, nullptr);
    }
}

// ---------------------------------------------------------------------------
// Fused ts2 + pe_gemm + combine. grid (16,24), BM=32, BN=64.
// te = h1@Wt2^T + bt2 (K=1024, B f32 staged);
// pe = pfe@Wpfe^T + ef@Wproj^T + bproj (two K=128 phases, all bf16);
// outputs: out_te (f32), out_pe (pad rows zeroed), out_x = embed + te + pe.
// smem pool: phase1 13824 B; phase2 sA[32][136]@0 + sB[64][136]@8704 = 26112 B.
// ---------------------------------------------------------------------------
__global__ __launch_bounds__(256) void ts2_pe_kernel(
    const unsigned short* __restrict__ h1_bf,
    const float* __restrict__ Wt2,
    const float* __restrict__ bt2,
    const unsigned short* __restrict__ pfe_bf,
    const unsigned short* __restrict__ ef_bf,
    const unsigned short* __restrict__ Wpfebf,
    const unsigned short* __restrict__ Wprojbf,
    const float* __restrict__ bproj,
    const int* __restrict__ token,
    const float* __restrict__ embed_w,
    float* __restrict__ outTE,
    float* __restrict__ outPE,
    float* __restrict__ outX)
{
    __shared__ __align__(16) char smem[26112];
    const int tid  = threadIdx.x;
    const int lane = tid & 63;
    const int wave = tid >> 6;
    const int l15  = lane & 15;
    const int quad = lane >> 4;
    const int mt   = wave & 1;
    const int np   = wave >> 1;
    const int m0 = blockIdx.y * 32, n0 = blockIdx.x * 64;

    // ---- phase 1: te accumulation (K=1024)
    f32x4 accTE[2];
    gemm_ts_body(smem, m0, n0, h1_bf, Wt2, bt2, nullptr, D_, D_, 0, accTE);

    // ---- phase 2: pe accumulation (two K=128 passes, bf16)
    unsigned short (*sA2)[136] = (unsigned short(*)[136])smem;
    unsigned short (*sB2)[136] = (unsigned short(*)[136])(smem + 8704);
    f32x4 accPE[2];
#pragma unroll
    for (int t = 0; t < 2; ++t) accPE[t] = (f32x4){0.f, 0.f, 0.f, 0.f};

    for (int phase = 0; phase < 2; ++phase) {
        const unsigned short* Ap = phase ? ef_bf : pfe_bf;
        const unsigned short* Bp = phase ? Wprojbf : Wpfebf;
#pragma unroll
        for (int e = tid; e < 512; e += 256) {
            const int r = e >> 4, c8 = (e & 15) * 8;
            *(uint4*)&sA2[r][c8] = *(const uint4*)&Ap[(size_t)(m0 + r) * K_ + c8];
        }
#pragma unroll
        for (int e = tid; e < 1024; e += 256) {
            const int r = e >> 4, c8 = (e & 15) * 8;
            *(uint4*)&sB2[r][c8] = *(const uint4*)&Bp[(size_t)(n0 + r) * K_ + c8];
        }
        __syncthreads();
#pragma unroll
        for (int ks = 0; ks < 4; ++ks) {
            const bf16x8 av = *(const bf16x8*)&sA2[mt * 16 + l15][ks * 32 + quad * 8];
#pragma unroll
            for (int t = 0; t < 2; ++t) {
                const bf16x8 bv = *(const bf16x8*)&sB2[(np * 2 + t) * 16 + l15][ks * 32 + quad * 8];
                accPE[t] = __builtin_amdgcn_mfma_f32_16x16x32_bf16(av, bv, accPE[t], 0, 0, 0);
            }
        }
        __syncthreads();
    }

    // ---- epilogue: te, pe, x
#pragma unroll
    for (int t = 0; t < 2; ++t) {
        const int nc = n0 + (np * 2 + t) * 16 + l15;
        const float bte = bt2[nc];
        const float bpe = bproj[nc];
#pragma unroll
        for (int r = 0; r < 4; ++r) {
            const int mr = m0 + mt * 16 + quad * 4 + r;
            const int tok = token[mr];
            const float te = accTE[t][r] + bte;
            const float pe = (tok == 0) ? 0.0f : (accPE[t][r] + bpe);
            outTE[(size_t)mr * D_ + nc] = te;
            outPE[(size_t)mr * D_ + nc] = pe;
            outX[(size_t)mr * D_ + nc] = embed_w[(size_t)tok * D_ + nc] + te + pe;
        }
    }
}

// ---------------------------------------------------------------------------
extern "C" void kernel_launch(void* const* d_in, const int* in_sizes, int n_in,
                              void* d_out, int out_size, void* d_ws, size_t ws_size,
                              hipStream_t stream) {
    const int*           token_id    = (const int*)d_in[0];
    const unsigned char* is_periodic = (const unsigned char*)d_in[1];
    const float*         pos         = (const float*)d_in[2];
    const unsigned char* adj         = (const unsigned char*)d_in[3];
    const int*           nte         = (const int*)d_in[4];
    const float*         time_step   = (const float*)d_in[5];
    const unsigned char* clean_mask  = (const unsigned char*)d_in[6];
    const float*         embed_w     = (const float*)d_in[7];
    const float*         Wpos        = (const float*)d_in[8];
    const float*         Wpfe        = (const float*)d_in[9];
    const float*         gbf_means   = (const float*)d_in[10];
    const float*         gbf_stds    = (const float*)d_in[11];
    const float*         gbf_mul     = (const float*)d_in[12];
    const float*         gbf_bias    = (const float*)d_in[13];
    const float*         W1          = (const float*)d_in[14];
    const float*         b1          = (const float*)d_in[15];
    const float*         W2          = (const float*)d_in[16];
    const float*         b2          = (const float*)d_in[17];
    const float*         Wproj       = (const float*)d_in[18];
    const float*         bproj       = (const float*)d_in[19];
    const float*         Wt1         = (const float*)d_in[20];
    const float*         bt1         = (const float*)d_in[21];
    const float*         Wt2         = (const float*)d_in[22];
    const float*         bt2         = (const float*)d_in[23];

    float* out = (float*)d_out;
    float* out_x   = out;                 // (B,L,D)
    float* out_pad = out + 786432;        // (B,L)
    float* out_te  = out + 787200;        // (B,L,D)
    float* out_pab = out + 1573632;       // (B,H,L,L)
    float* out_pe  = out + 11010816;      // (B,L,D)

    // workspace (ushort units), ~4.1 MB
    unsigned short* wsu = (unsigned short*)d_ws;
    unsigned short* W1bf    = wsu;                 // 16384
    unsigned short* W2bf    = wsu + 16384;         // 4096
    unsigned short* Wpfebf  = wsu + 20480;         // 131072
    unsigned short* Wprojbf = wsu + 151552;        // 131072
    unsigned short* sin_bf  = wsu + 282624;        // 786432
    unsigned short* h1_bf   = wsu + 1069056;       // 786432
    unsigned short* pfe_bf  = wsu + 1855488;       // 98304
    unsigned short* ef_bf   = wsu + 1953792;       // 98304

    prep_sin_kernel<<<dim3(1044), dim3(256), 0, stream>>>(
        W1, W2, Wpfe, Wproj, W1bf, W2bf, Wpfebf, Wprojbf,
        time_step, clean_mask, token_id, sin_bf, out_pad);
    edge_ts1<<<dim3(B_ * L_ + 384), dim3(256), 0, stream>>>(
        token_id, is_periodic, pos, adj, nte, gbf_means, gbf_stds, gbf_mul, gbf_bias,
        b1, b2, Wpos, W1bf, W2bf, pfe_bf, ef_bf, out_pab,
        sin_bf, Wt1, bt1, h1_bf);
    ts2_pe_kernel<<<dim3(16, 24), dim3(256), 0, stream>>>(
        h1_bf, Wt2, bt2, pfe_bf, ef_bf, Wpfebf, Wprojbf, bproj, token_id, embed_w,
        out_te, out_pe, out_x);
}